// Round 5
// baseline (1086.298 us; speedup 1.0000x reference)
//
#include <hip/hip_runtime.h>

using short8 = __attribute__((ext_vector_type(8))) short;
using f32x4  = __attribute__((ext_vector_type(4))) float;

static __device__ __forceinline__ short f2bf(float f) {
  unsigned u = __float_as_uint(f);
  u += 0x7fffu + ((u >> 16) & 1u);   // RNE to bf16
  return (short)(u >> 16);
}
static __device__ __forceinline__ float bf2f(short s) {
  return __uint_as_float(((unsigned)(unsigned short)s) << 16);
}
static __device__ __forceinline__ float us2f(unsigned short s) {
  return __uint_as_float(((unsigned)s) << 16);
}
static __device__ __forceinline__ short8 load8_bf16(const float* __restrict__ p) {
  const f32x4* q = (const f32x4*)p;
  f32x4 a = q[0], b = q[1];
  short8 r;
  r[0]=f2bf(a[0]); r[1]=f2bf(a[1]); r[2]=f2bf(a[2]); r[3]=f2bf(a[3]);
  r[4]=f2bf(b[0]); r[5]=f2bf(b[1]); r[6]=f2bf(b[2]); r[7]=f2bf(b[3]);
  return r;
}
// hi/lo bf16 split: v ~= hi + lo
static __device__ __forceinline__ void split8(const float* p, short8& hi, short8& lo) {
  const f32x4* q = (const f32x4*)p;
  f32x4 a = q[0], b = q[1];
  float v[8] = {a[0],a[1],a[2],a[3],b[0],b[1],b[2],b[3]};
#pragma unroll
  for (int j = 0; j < 8; ++j) {
    short h = f2bf(v[j]);
    hi[j] = h;
    lo[j] = f2bf(v[j] - bf2f(h));
  }
}

// ---------------- node encoder: h = relu(X @ Wn^T + bn), MFMA, A-split ----------------
__global__ __launch_bounds__(256) void node_encode(
    const float* __restrict__ X, const float* __restrict__ Wn,
    const float* __restrict__ bn, float* __restrict__ h,
    unsigned short* __restrict__ hb, int nNodes) {
  int tid = threadIdx.x, lane = tid & 63, w = tid >> 6, lg = lane >> 4, lr = lane & 15;
  short8 bf[4][4];
#pragma unroll
  for (int t = 0; t < 4; ++t)
#pragma unroll
    for (int kk = 0; kk < 4; ++kk)
      bf[t][kk] = load8_bf16(Wn + (t*16+lr)*128 + kk*32 + lg*8);
  float bias[4];
#pragma unroll
  for (int t = 0; t < 4; ++t) bias[t] = bn[t*16+lr];

  int base = blockIdx.x * 64 + w * 16;
  int arow = base + lr;
  int nn = arow < nNodes ? arow : nNodes - 1;
  f32x4 acc[4] = {};
#pragma unroll
  for (int kk = 0; kk < 4; ++kk) {
    short8 aH, aL;
    split8(X + (size_t)nn*128 + kk*32 + lg*8, aH, aL);
#pragma unroll
    for (int t = 0; t < 4; ++t) {
      acc[t] = __builtin_amdgcn_mfma_f32_16x16x32_bf16(aH, bf[t][kk], acc[t], 0, 0, 0);
      acc[t] = __builtin_amdgcn_mfma_f32_16x16x32_bf16(aL, bf[t][kk], acc[t], 0, 0, 0);
    }
  }
#pragma unroll
  for (int t = 0; t < 4; ++t)
#pragma unroll
    for (int i = 0; i < 4; ++i) {
      int orow = base + lg*4 + i;
      if (orow < nNodes) {
        float v = fmaxf(acc[t][i] + bias[t], 0.f);
        h[(size_t)orow*64 + t*16 + lr] = v;
        hb[(size_t)orow*64 + t*16 + lr] = (unsigned short)f2bf(v);
      }
    }
}

// ---------------- CSR build ----------------
__global__ __launch_bounds__(256) void hist_deg(
    const int* __restrict__ dst, int* __restrict__ deg, int nEdges) {
  for (int e = blockIdx.x*256 + threadIdx.x; e < nEdges; e += gridDim.x*256)
    atomicAdd(&deg[dst[e]], 1);
}

__global__ __launch_bounds__(256) void scan_pass1(
    const int* __restrict__ deg, int* __restrict__ bsum, int n) {
  int b = blockIdx.x, tid = threadIdx.x;
  int base = b * 4096;
  int s = 0;
  for (int j = tid; j < 4096; j += 256) {
    int i = base + j;
    s += (i < n) ? deg[i] : 0;
  }
  __shared__ int ws[4];
#pragma unroll
  for (int o = 32; o; o >>= 1) s += __shfl_down(s, o);
  if ((tid & 63) == 0) ws[tid >> 6] = s;
  __syncthreads();
  if (tid == 0) bsum[b] = ws[0] + ws[1] + ws[2] + ws[3];
}

__global__ void scan_pass2(const int* __restrict__ bsum, int* __restrict__ boff,
                           int* __restrict__ off, int nBlocks, int n) {
  if (threadIdx.x == 0 && blockIdx.x == 0) {
    int run = 0;
    for (int b = 0; b < nBlocks; ++b) { boff[b] = run; run += bsum[b]; }
    off[n] = run;
  }
}

__global__ __launch_bounds__(256) void scan_pass3(
    const int* __restrict__ deg, const int* __restrict__ boff,
    int* __restrict__ off, int n) {
  int b = blockIdx.x, tid = threadIdx.x;
  int lane = tid & 63, w = tid >> 6;
  int base = b * 4096 + tid * 16;
  int d[16], tot = 0;
#pragma unroll
  for (int j = 0; j < 16; ++j) {
    d[j] = (base + j < n) ? deg[base + j] : 0;
    tot += d[j];
  }
  int s = tot;
#pragma unroll
  for (int o = 1; o < 64; o <<= 1) {
    int t = __shfl_up(s, o);
    if (lane >= o) s += t;
  }
  __shared__ int ws[4];
  if (lane == 63) ws[w] = s;
  __syncthreads();
  int wo = 0;
  for (int k = 0; k < 4; ++k) wo += (k < w) ? ws[k] : 0;
  int run = boff[b] + wo + s - tot;
#pragma unroll
  for (int j = 0; j < 16; ++j) {
    if (base + j < n) off[base + j] = run;
    run += d[j];
  }
}

__global__ __launch_bounds__(256) void fill_csr(
    const int* __restrict__ src, const int* __restrict__ dst,
    const int* __restrict__ off, int* __restrict__ cursor,
    int2* __restrict__ ep, int nEdges) {
  for (int e = blockIdx.x*256 + threadIdx.x; e < nEdges; e += gridDim.x*256) {
    int d = dst[e];
    int pos = off[d] + atomicAdd(&cursor[d], 1);
    int2 v; v.x = e; v.y = src[e];
    ep[pos] = v;
  }
}

#define ETILE 128
__global__ __launch_bounds__(256) void tile_nlo_k(
    const int* __restrict__ off, int* __restrict__ tnlo, int nNodes, int nTiles) {
  int t = blockIdx.x*256 + threadIdx.x;
  if (t > nTiles) return;
  int e0 = t * ETILE;
  int lo = 0, hi = nNodes - 1;
  while (lo < hi) { int m = (lo + hi) >> 1; if (off[m+1] > e0) hi = m; else lo = m + 1; }
  tnlo[t] = lo;
}

// ---------------- edge encoder fused with segment-sum (MFMA, A-split) ----------------
__global__ __launch_bounds__(256) void edge_encode_fused(
    const float* __restrict__ EA, const float* __restrict__ We,
    const float* __restrict__ be, const int* __restrict__ off,
    const int2* __restrict__ ep, const int* __restrict__ tnlo,
    float* __restrict__ Esum, int nNodes, int nEdges) {
  __shared__ float tile[ETILE][66];
  int tid = threadIdx.x, lane = tid & 63, w = tid >> 6;
  int lr = lane & 15, lg = lane >> 4;

  short8 bf[4][2];
#pragma unroll
  for (int t = 0; t < 4; ++t)
#pragma unroll
    for (int kk = 0; kk < 2; ++kk)
      bf[t][kk] = load8_bf16(We + (t*16+lr)*64 + kk*32 + lg*8);
  float bias[4];
#pragma unroll
  for (int t = 0; t < 4; ++t) bias[t] = be[t*16+lr];

  int e0 = blockIdx.x * ETILE;
  int e1 = e0 + ETILE; if (e1 > nEdges) e1 = nEdges;
  int er0 = e0 + w*32 + lr;
  int er1 = er0 + 16;
  int ei0 = ep[er0 < nEdges ? er0 : nEdges-1].x;
  int ei1 = ep[er1 < nEdges ? er1 : nEdges-1].x;
  const float* r0p = EA + (size_t)ei0*64;
  const float* r1p = EA + (size_t)ei1*64;
  short8 aH[2][2], aL[2][2];
#pragma unroll
  for (int kk = 0; kk < 2; ++kk) {
    split8(r0p + kk*32 + lg*8, aH[0][kk], aL[0][kk]);
    split8(r1p + kk*32 + lg*8, aH[1][kk], aL[1][kk]);
  }
  f32x4 acc[2][4] = {};
#pragma unroll
  for (int b = 0; b < 2; ++b)
#pragma unroll
    for (int kk = 0; kk < 2; ++kk)
#pragma unroll
      for (int t = 0; t < 4; ++t) {
        acc[b][t] = __builtin_amdgcn_mfma_f32_16x16x32_bf16(aH[b][kk], bf[t][kk], acc[b][t], 0,0,0);
        acc[b][t] = __builtin_amdgcn_mfma_f32_16x16x32_bf16(aL[b][kk], bf[t][kk], acc[b][t], 0,0,0);
      }
#pragma unroll
  for (int b = 0; b < 2; ++b)
#pragma unroll
    for (int t = 0; t < 4; ++t)
#pragma unroll
      for (int i = 0; i < 4; ++i)
        tile[w*32 + b*16 + lg*4 + i][t*16 + lr] = fmaxf(acc[b][t][i] + bias[t], 0.f);
  __syncthreads();

  int nlo = tnlo[blockIdx.x], nhi = tnlo[blockIdx.x + 1];
  for (int n = nlo + w; n <= nhi; n += 4) {
    int a = off[n], b2 = off[n+1];
    int ra = (a > e0 ? a : e0) - e0;
    int rb = (b2 < e1 ? b2 : e1) - e0;
    float s = 0.f;
    int r = ra;
    for (; r + 4 <= rb; r += 4)
      s += tile[r][lane] + tile[r+1][lane] + tile[r+2][lane] + tile[r+3][lane];
    for (; r < rb; ++r) s += tile[r][lane];
    bool interior = (a >= e0) && (b2 <= e1);
    float* p = &Esum[(size_t)n*64 + lane];
    if (interior) *p = s;
    else if (rb > ra) atomicAdd(p, s);
  }
}

// ---------------- weight combos (hi/lo bf16 splits) ----------------
__global__ __launch_bounds__(256) void make_combos(
    const float* __restrict__ wih, const float* __restrict__ Wagg,
    const float* __restrict__ bagg, const float* __restrict__ whh,
    short* __restrict__ WceH, short* __restrict__ WceL,
    short* __restrict__ WchH, short* __restrict__ WchL,
    short* __restrict__ whhH, short* __restrict__ whhL, float* __restrict__ bihA) {
  int idx = blockIdx.x*256 + threadIdx.x;
  if (idx < 12288) {
    int r = idx >> 6, k = idx & 63;
    float a = 0.f, b = 0.f;
    for (int j = 0; j < 64; ++j) {
      float ww = wih[r*64 + j];
      a += ww * Wagg[j*128 + k];
      b += ww * Wagg[j*128 + 64 + k];
    }
    short ah = f2bf(a);
    WchH[idx] = ah; WchL[idx] = f2bf(a - bf2f(ah));
    short bh = f2bf(b);
    WceH[idx] = bh; WceL[idx] = f2bf(b - bf2f(bh));
    float wv = whh[idx];
    short hh = f2bf(wv);
    whhH[idx] = hh; whhL[idx] = f2bf(wv - bf2f(hh));
    if (idx < 192) {
      float s = 0.f;
      for (int j = 0; j < 64; ++j) s += wih[idx*64 + j] * bagg[j];
      bihA[idx] = s;
    }
  }
}

// ---------------- fused layer: bf16 gather + MFMA (gi & gh) + GRU ----------------
__global__ __launch_bounds__(256) void layer_fused(
    const float* __restrict__ h_old, const unsigned short* __restrict__ h_oldb,
    const float* __restrict__ Esum,
    const int* __restrict__ off, const int2* __restrict__ ep,
    const int* __restrict__ deg,
    const short* __restrict__ WceH, const short* __restrict__ WceL,
    const short* __restrict__ WchH, const short* __restrict__ WchL,
    const short* __restrict__ whhH, const short* __restrict__ whhL,
    const float* __restrict__ bihA, const float* __restrict__ bih,
    const float* __restrict__ bhh, float* __restrict__ h_new,
    unsigned short* __restrict__ h_newb, int nNodes) {
  __shared__ float G[64][68];
  int tid = threadIdx.x, lane = tid & 63, w = tid >> 6;
  int lr = lane & 15, lg = lane >> 4;
  int nb = blockIdx.x * 64;

  // gather Sum h[src] in bf16 (12.8MB array ~ L2-resident), 8-deep unroll
  for (int i = 0; i < 16; ++i) {
    int n = nb + w*16 + i;
    float s0 = 0.f, s1 = 0.f;
    if (n < nNodes) {
      int a = off[n], b = off[n+1], idx = a;
      for (; idx + 8 <= b; idx += 8) {
        int e0 = ep[idx].y,   e1 = ep[idx+1].y, e2 = ep[idx+2].y, e3 = ep[idx+3].y;
        int e4 = ep[idx+4].y, e5 = ep[idx+5].y, e6 = ep[idx+6].y, e7 = ep[idx+7].y;
        unsigned short u0 = h_oldb[(size_t)e0*64 + lane];
        unsigned short u1 = h_oldb[(size_t)e1*64 + lane];
        unsigned short u2 = h_oldb[(size_t)e2*64 + lane];
        unsigned short u3 = h_oldb[(size_t)e3*64 + lane];
        unsigned short u4 = h_oldb[(size_t)e4*64 + lane];
        unsigned short u5 = h_oldb[(size_t)e5*64 + lane];
        unsigned short u6 = h_oldb[(size_t)e6*64 + lane];
        unsigned short u7 = h_oldb[(size_t)e7*64 + lane];
        s0 += us2f(u0) + us2f(u2) + us2f(u4) + us2f(u6);
        s1 += us2f(u1) + us2f(u3) + us2f(u5) + us2f(u7);
      }
      for (; idx < b; ++idx)
        s0 += us2f(h_oldb[(size_t)ep[idx].y*64 + lane]);
    }
    G[w*16 + i][lane] = s0 + s1;
  }
  __syncthreads();

  int arow = nb + w*16 + lr; if (arow >= nNodes) arow = nNodes - 1;
  short8 EsH[2], EsL[2], GHf[2], GLf[2], HH[2], HL[2];
#pragma unroll
  for (int kk = 0; kk < 2; ++kk) {
    split8(Esum + (size_t)arow*64 + kk*32 + lg*8, EsH[kk], EsL[kk]);
    split8(&G[w*16 + lr][kk*32 + lg*8], GHf[kk], GLf[kk]);
    split8(h_old + (size_t)arow*64 + kk*32 + lg*8, HH[kk], HL[kk]);
  }

  int row0 = nb + w*16 + lg*4;
  float degv[4];
#pragma unroll
  for (int i = 0; i < 4; ++i) {
    int n = row0 + i;
    degv[i] = (n < nNodes) ? (float)deg[n] : 0.f;
  }

  f32x4 gi[12], gh[12];
#pragma unroll
  for (int ct = 0; ct < 12; ++ct) {
    float bi = bih[ct*16 + lr], ba = bihA[ct*16 + lr], bh = bhh[ct*16 + lr];
#pragma unroll
    for (int i = 0; i < 4; ++i) { gi[ct][i] = bi + degv[i]*ba; gh[ct][i] = bh; }
  }

#pragma unroll
  for (int ct = 0; ct < 12; ++ct) {
    int wb = (ct*16 + lr)*64 + lg*8;
#pragma unroll
    for (int kk = 0; kk < 2; ++kk) {
      int o = wb + kk*32;
      short8 wceh = *(const short8*)(WceH + o);
      short8 wcel = *(const short8*)(WceL + o);
      short8 wchh = *(const short8*)(WchH + o);
      short8 wchl = *(const short8*)(WchL + o);
      short8 whh_h = *(const short8*)(whhH + o);
      short8 whh_l = *(const short8*)(whhL + o);
      gi[ct] = __builtin_amdgcn_mfma_f32_16x16x32_bf16(EsH[kk], wceh, gi[ct], 0,0,0);
      gi[ct] = __builtin_amdgcn_mfma_f32_16x16x32_bf16(EsL[kk], wceh, gi[ct], 0,0,0);
      gi[ct] = __builtin_amdgcn_mfma_f32_16x16x32_bf16(EsH[kk], wcel, gi[ct], 0,0,0);
      gi[ct] = __builtin_amdgcn_mfma_f32_16x16x32_bf16(GHf[kk], wchh, gi[ct], 0,0,0);
      gi[ct] = __builtin_amdgcn_mfma_f32_16x16x32_bf16(GLf[kk], wchh, gi[ct], 0,0,0);
      gi[ct] = __builtin_amdgcn_mfma_f32_16x16x32_bf16(GHf[kk], wchl, gi[ct], 0,0,0);
      gh[ct] = __builtin_amdgcn_mfma_f32_16x16x32_bf16(HH[kk], whh_h, gh[ct], 0,0,0);
      gh[ct] = __builtin_amdgcn_mfma_f32_16x16x32_bf16(HL[kk], whh_h, gh[ct], 0,0,0);
      gh[ct] = __builtin_amdgcn_mfma_f32_16x16x32_bf16(HH[kk], whh_l, gh[ct], 0,0,0);
    }
  }

  // GRU elementwise: lane holds cols ct*16+lr for rows row0..row0+3
#pragma unroll
  for (int ct = 0; ct < 4; ++ct)
#pragma unroll
    for (int i = 0; i < 4; ++i) {
      int n = row0 + i;
      if (n < nNodes) {
        int jh = ct*16 + lr;
        float r = 1.f/(1.f + expf(-(gi[ct][i] + gh[ct][i])));
        float z = 1.f/(1.f + expf(-(gi[ct+4][i] + gh[ct+4][i])));
        float nn = tanhf(gi[ct+8][i] + r * gh[ct+8][i]);
        float hv = h_old[(size_t)n*64 + jh];
        float hn = (1.f - z)*nn + z*hv;
        h_new[(size_t)n*64 + jh] = hn;
        h_newb[(size_t)n*64 + jh] = (unsigned short)f2bf(hn);
      }
    }
}

__global__ __launch_bounds__(256) void out_mlp(
    const float* __restrict__ h, const int* __restrict__ pm,
    const float* __restrict__ W1, const float* __restrict__ b1,
    const float* __restrict__ W2, const float* __restrict__ b2,
    float* __restrict__ out, int nPosts) {
  int tid = threadIdx.x;
  int lane = tid & 63;
  int p = blockIdx.x*4 + (tid >> 6);
  if (p >= nPosts) return;
  int n = pm[p];
  float v = h[(size_t)n*64 + lane];
  int row = lane & 31;
  float o = b1[row];
#pragma unroll
  for (int k = 0; k < 64; ++k) {
    float vb = __shfl(v, k);
    o += vb * W1[row*64 + k];
  }
  o = fmaxf(o, 0.f);
  float val = o * W2[row] * 0.5f;  // each row computed twice -> halve
#pragma unroll
  for (int offm = 32; offm > 0; offm >>= 1) val += __shfl_xor(val, offm);
  if (lane == 0) out[p] = 1.f/(1.f + expf(-(val + b2[0])));
}

static inline char* aln(char*& w, size_t bytes) {
  uintptr_t p = ((uintptr_t)w + 255) & ~(uintptr_t)255;
  char* r = (char*)p;
  w = r + bytes;
  return r;
}

extern "C" void kernel_launch(void* const* d_in, const int* in_sizes, int n_in,
                              void* d_out, int out_size, void* d_ws, size_t ws_size,
                              hipStream_t stream) {
  const float* X    = (const float*)d_in[0];
  const float* EA   = (const float*)d_in[1];
  const int*   EI   = (const int*)d_in[2];
  const int*   PM   = (const int*)d_in[3];
  const float* Wn   = (const float*)d_in[5];
  const float* bn   = (const float*)d_in[6];
  const float* We   = (const float*)d_in[7];
  const float* be   = (const float*)d_in[8];
  const float* Wagg = (const float*)d_in[9];
  const float* bagg = (const float*)d_in[10];
  const float* wih  = (const float*)d_in[11];
  const float* whh  = (const float*)d_in[12];
  const float* bih  = (const float*)d_in[13];
  const float* bhh  = (const float*)d_in[14];
  const float* W1   = (const float*)d_in[15];
  const float* b1   = (const float*)d_in[16];
  const float* W2   = (const float*)d_in[17];
  const float* b2   = (const float*)d_in[18];
  float* out = (float*)d_out;

  int nNodes = in_sizes[0] / 128;
  int nEdges = in_sizes[1] / 64;
  int nPosts = in_sizes[3];
  const int* src = EI;
  const int* dst = EI + nEdges;
  int nTiles = (nEdges + ETILE - 1) / ETILE;
  int nSB = (nNodes + 4095) / 4096;

  char* w = (char*)d_ws;
  float* h0   = (float*)aln(w, (size_t)nNodes * 64 * 4);
  float* h1   = (float*)aln(w, (size_t)nNodes * 64 * 4);
  unsigned short* h0b = (unsigned short*)aln(w, (size_t)nNodes * 64 * 2);
  unsigned short* h1b = (unsigned short*)aln(w, (size_t)nNodes * 64 * 2);
  float* Esum = (float*)aln(w, (size_t)nNodes * 64 * 4);
  short* WceH = (short*)aln(w, 12288 * 2);
  short* WceL = (short*)aln(w, 12288 * 2);
  short* WchH = (short*)aln(w, 12288 * 2);
  short* WchL = (short*)aln(w, 12288 * 2);
  short* whhH = (short*)aln(w, 12288 * 2);
  short* whhL = (short*)aln(w, 12288 * 2);
  float* bihA = (float*)aln(w, 192 * 4);
  int*   off  = (int*)aln(w, (size_t)(nNodes + 1) * 4);
  int*   deg  = (int*)aln(w, (size_t)nNodes * 4);
  int*   cur  = (int*)aln(w, (size_t)nNodes * 4);
  int2*  ep   = (int2*)aln(w, (size_t)nEdges * 8);
  int*   tnlo = (int*)aln(w, (size_t)(nTiles + 1) * 4);
  int*   bsum = (int*)aln(w, (size_t)nSB * 4);
  int*   boff = (int*)aln(w, (size_t)nSB * 4);

  hipMemsetAsync(deg, 0, (size_t)nNodes * 4, stream);
  hipMemsetAsync(cur, 0, (size_t)nNodes * 4, stream);
  hipMemsetAsync(Esum, 0, (size_t)nNodes * 64 * 4, stream);

  hist_deg<<<2048, 256, 0, stream>>>(dst, deg, nEdges);
  scan_pass1<<<nSB, 256, 0, stream>>>(deg, bsum, nNodes);
  scan_pass2<<<1, 1, 0, stream>>>(bsum, boff, off, nSB, nNodes);
  scan_pass3<<<nSB, 256, 0, stream>>>(deg, boff, off, nNodes);
  fill_csr<<<2048, 256, 0, stream>>>(src, dst, off, cur, ep, nEdges);
  tile_nlo_k<<<(nTiles + 256) / 256, 256, 0, stream>>>(off, tnlo, nNodes, nTiles);

  node_encode<<<(nNodes + 63) / 64, 256, 0, stream>>>(X, Wn, bn, h0, h0b, nNodes);
  edge_encode_fused<<<nTiles, 256, 0, stream>>>(EA, We, be, off, ep, tnlo, Esum,
                                                nNodes, nEdges);
  make_combos<<<48, 256, 0, stream>>>(wih, Wagg, bagg, whh,
                                      WceH, WceL, WchH, WchL, whhH, whhL, bihA);

  layer_fused<<<(nNodes + 63) / 64, 256, 0, stream>>>(
      h0, h0b, Esum, off, ep, deg, WceH, WceL, WchH, WchL, whhH, whhL,
      bihA, bih, bhh, h1, h1b, nNodes);
  layer_fused<<<(nNodes + 63) / 64, 256, 0, stream>>>(
      h1, h1b, Esum, off, ep, deg, WceH, WceL, WchH, WchL, whhH, whhL,
      bihA, bih, bhh, h0, h0b, nNodes);

  out_mlp<<<(nPosts + 3) / 4, 256, 0, stream>>>(h0, PM, W1, b1, W2, b2, out, nPosts);
}

// Round 6
// 815.020 us; speedup vs baseline: 1.3328x; 1.3328x over previous
//
#include <hip/hip_runtime.h>

using short8  = __attribute__((ext_vector_type(8))) short;
using ushort8 = __attribute__((ext_vector_type(8))) unsigned short;
using f32x4   = __attribute__((ext_vector_type(4))) float;

static __device__ __forceinline__ short f2bf(float f) {
  unsigned u = __float_as_uint(f);
  u += 0x7fffu + ((u >> 16) & 1u);   // RNE to bf16
  return (short)(u >> 16);
}
static __device__ __forceinline__ float bf2f(short s) {
  return __uint_as_float(((unsigned)(unsigned short)s) << 16);
}
static __device__ __forceinline__ float us2f(unsigned short s) {
  return __uint_as_float(((unsigned)s) << 16);
}
static __device__ __forceinline__ short8 load8_bf16(const float* __restrict__ p) {
  const f32x4* q = (const f32x4*)p;
  f32x4 a = q[0], b = q[1];
  short8 r;
  r[0]=f2bf(a[0]); r[1]=f2bf(a[1]); r[2]=f2bf(a[2]); r[3]=f2bf(a[3]);
  r[4]=f2bf(b[0]); r[5]=f2bf(b[1]); r[6]=f2bf(b[2]); r[7]=f2bf(b[3]);
  return r;
}
// hi/lo bf16 split: v ~= hi + lo
static __device__ __forceinline__ void split8(const float* p, short8& hi, short8& lo) {
  const f32x4* q = (const f32x4*)p;
  f32x4 a = q[0], b = q[1];
  float v[8] = {a[0],a[1],a[2],a[3],b[0],b[1],b[2],b[3]};
#pragma unroll
  for (int j = 0; j < 8; ++j) {
    short h = f2bf(v[j]);
    hi[j] = h;
    lo[j] = f2bf(v[j] - bf2f(h));
  }
}

// ---------------- node encoder: h = relu(X @ Wn^T + bn), MFMA, A-split ----------------
__global__ __launch_bounds__(256) void node_encode(
    const float* __restrict__ X, const float* __restrict__ Wn,
    const float* __restrict__ bn, float* __restrict__ h,
    unsigned short* __restrict__ hb, int nNodes) {
  int tid = threadIdx.x, lane = tid & 63, w = tid >> 6, lg = lane >> 4, lr = lane & 15;
  short8 bf[4][4];
#pragma unroll
  for (int t = 0; t < 4; ++t)
#pragma unroll
    for (int kk = 0; kk < 4; ++kk)
      bf[t][kk] = load8_bf16(Wn + (t*16+lr)*128 + kk*32 + lg*8);
  float bias[4];
#pragma unroll
  for (int t = 0; t < 4; ++t) bias[t] = bn[t*16+lr];

  int base = blockIdx.x * 64 + w * 16;
  int arow = base + lr;
  int nn = arow < nNodes ? arow : nNodes - 1;
  f32x4 acc[4] = {};
#pragma unroll
  for (int kk = 0; kk < 4; ++kk) {
    short8 aH, aL;
    split8(X + (size_t)nn*128 + kk*32 + lg*8, aH, aL);
#pragma unroll
    for (int t = 0; t < 4; ++t) {
      acc[t] = __builtin_amdgcn_mfma_f32_16x16x32_bf16(aH, bf[t][kk], acc[t], 0, 0, 0);
      acc[t] = __builtin_amdgcn_mfma_f32_16x16x32_bf16(aL, bf[t][kk], acc[t], 0, 0, 0);
    }
  }
#pragma unroll
  for (int t = 0; t < 4; ++t)
#pragma unroll
    for (int i = 0; i < 4; ++i) {
      int orow = base + lg*4 + i;
      if (orow < nNodes) {
        float v = fmaxf(acc[t][i] + bias[t], 0.f);
        h[(size_t)orow*64 + t*16 + lr] = v;
        hb[(size_t)orow*64 + t*16 + lr] = (unsigned short)f2bf(v);
      }
    }
}

// ---------------- CSR build ----------------
__global__ __launch_bounds__(256) void hist_deg(
    const int* __restrict__ dst, int* __restrict__ deg, int nEdges) {
  for (int e = blockIdx.x*256 + threadIdx.x; e < nEdges; e += gridDim.x*256)
    atomicAdd(&deg[dst[e]], 1);
}

__global__ __launch_bounds__(256) void scan_pass1(
    const int* __restrict__ deg, int* __restrict__ bsum, int n) {
  int b = blockIdx.x, tid = threadIdx.x;
  int base = b * 4096;
  int s = 0;
  for (int j = tid; j < 4096; j += 256) {
    int i = base + j;
    s += (i < n) ? deg[i] : 0;
  }
  __shared__ int ws[4];
#pragma unroll
  for (int o = 32; o; o >>= 1) s += __shfl_down(s, o);
  if ((tid & 63) == 0) ws[tid >> 6] = s;
  __syncthreads();
  if (tid == 0) bsum[b] = ws[0] + ws[1] + ws[2] + ws[3];
}

__global__ void scan_pass2(const int* __restrict__ bsum, int* __restrict__ boff,
                           int* __restrict__ off, int nBlocks, int n) {
  if (threadIdx.x == 0 && blockIdx.x == 0) {
    int run = 0;
    for (int b = 0; b < nBlocks; ++b) { boff[b] = run; run += bsum[b]; }
    off[n] = run;
  }
}

__global__ __launch_bounds__(256) void scan_pass3(
    const int* __restrict__ deg, const int* __restrict__ boff,
    int* __restrict__ off, int n) {
  int b = blockIdx.x, tid = threadIdx.x;
  int lane = tid & 63, w = tid >> 6;
  int base = b * 4096 + tid * 16;
  int d[16], tot = 0;
#pragma unroll
  for (int j = 0; j < 16; ++j) {
    d[j] = (base + j < n) ? deg[base + j] : 0;
    tot += d[j];
  }
  int s = tot;
#pragma unroll
  for (int o = 1; o < 64; o <<= 1) {
    int t = __shfl_up(s, o);
    if (lane >= o) s += t;
  }
  __shared__ int ws[4];
  if (lane == 63) ws[w] = s;
  __syncthreads();
  int wo = 0;
  for (int k = 0; k < 4; ++k) wo += (k < w) ? ws[k] : 0;
  int run = boff[b] + wo + s - tot;
#pragma unroll
  for (int j = 0; j < 16; ++j) {
    if (base + j < n) off[base + j] = run;
    run += d[j];
  }
}

__global__ __launch_bounds__(256) void fill_csr(
    const int* __restrict__ src, const int* __restrict__ dst,
    const int* __restrict__ off, int* __restrict__ cursor,
    int2* __restrict__ ep, int nEdges) {
  for (int e = blockIdx.x*256 + threadIdx.x; e < nEdges; e += gridDim.x*256) {
    int d = dst[e];
    int pos = off[d] + atomicAdd(&cursor[d], 1);
    int2 v; v.x = e; v.y = src[e];
    ep[pos] = v;
  }
}

#define ETILE 128
__global__ __launch_bounds__(256) void tile_nlo_k(
    const int* __restrict__ off, int* __restrict__ tnlo, int nNodes, int nTiles) {
  int t = blockIdx.x*256 + threadIdx.x;
  if (t > nTiles) return;
  int e0 = t * ETILE;
  int lo = 0, hi = nNodes - 1;
  while (lo < hi) { int m = (lo + hi) >> 1; if (off[m+1] > e0) hi = m; else lo = m + 1; }
  tnlo[t] = lo;
}

// ---------------- edge encoder fused with segment-sum (MFMA, A-split) ----------------
__global__ __launch_bounds__(256) void edge_encode_fused(
    const float* __restrict__ EA, const float* __restrict__ We,
    const float* __restrict__ be, const int* __restrict__ off,
    const int2* __restrict__ ep, const int* __restrict__ tnlo,
    float* __restrict__ Esum, int nNodes, int nEdges) {
  __shared__ float tile[ETILE][66];
  int tid = threadIdx.x, lane = tid & 63, w = tid >> 6;
  int lr = lane & 15, lg = lane >> 4;

  short8 bf[4][2];
#pragma unroll
  for (int t = 0; t < 4; ++t)
#pragma unroll
    for (int kk = 0; kk < 2; ++kk)
      bf[t][kk] = load8_bf16(We + (t*16+lr)*64 + kk*32 + lg*8);
  float bias[4];
#pragma unroll
  for (int t = 0; t < 4; ++t) bias[t] = be[t*16+lr];

  int e0 = blockIdx.x * ETILE;
  int e1 = e0 + ETILE; if (e1 > nEdges) e1 = nEdges;
  int er0 = e0 + w*32 + lr;
  int er1 = er0 + 16;
  int ei0 = ep[er0 < nEdges ? er0 : nEdges-1].x;
  int ei1 = ep[er1 < nEdges ? er1 : nEdges-1].x;
  const float* r0p = EA + (size_t)ei0*64;
  const float* r1p = EA + (size_t)ei1*64;
  short8 aH[2][2], aL[2][2];
#pragma unroll
  for (int kk = 0; kk < 2; ++kk) {
    split8(r0p + kk*32 + lg*8, aH[0][kk], aL[0][kk]);
    split8(r1p + kk*32 + lg*8, aH[1][kk], aL[1][kk]);
  }
  f32x4 acc[2][4] = {};
#pragma unroll
  for (int b = 0; b < 2; ++b)
#pragma unroll
    for (int kk = 0; kk < 2; ++kk)
#pragma unroll
      for (int t = 0; t < 4; ++t) {
        acc[b][t] = __builtin_amdgcn_mfma_f32_16x16x32_bf16(aH[b][kk], bf[t][kk], acc[b][t], 0,0,0);
        acc[b][t] = __builtin_amdgcn_mfma_f32_16x16x32_bf16(aL[b][kk], bf[t][kk], acc[b][t], 0,0,0);
      }
#pragma unroll
  for (int b = 0; b < 2; ++b)
#pragma unroll
    for (int t = 0; t < 4; ++t)
#pragma unroll
      for (int i = 0; i < 4; ++i)
        tile[w*32 + b*16 + lg*4 + i][t*16 + lr] = fmaxf(acc[b][t][i] + bias[t], 0.f);
  __syncthreads();

  int nlo = tnlo[blockIdx.x], nhi = tnlo[blockIdx.x + 1];
  for (int n = nlo + w; n <= nhi; n += 4) {
    int a = off[n], b2 = off[n+1];
    int ra = (a > e0 ? a : e0) - e0;
    int rb = (b2 < e1 ? b2 : e1) - e0;
    float s = 0.f;
    int r = ra;
    for (; r + 4 <= rb; r += 4)
      s += tile[r][lane] + tile[r+1][lane] + tile[r+2][lane] + tile[r+3][lane];
    for (; r < rb; ++r) s += tile[r][lane];
    bool interior = (a >= e0) && (b2 <= e1);
    float* p = &Esum[(size_t)n*64 + lane];
    if (interior) *p = s;
    else if (rb > ra) atomicAdd(p, s);
  }
}

// ---------------- weight combos (hi/lo bf16 splits) ----------------
__global__ __launch_bounds__(256) void make_combos(
    const float* __restrict__ wih, const float* __restrict__ Wagg,
    const float* __restrict__ bagg, const float* __restrict__ whh,
    short* __restrict__ WceH, short* __restrict__ WceL,
    short* __restrict__ WchH, short* __restrict__ WchL,
    short* __restrict__ whhH, short* __restrict__ whhL, float* __restrict__ bihA) {
  int idx = blockIdx.x*256 + threadIdx.x;
  if (idx < 12288) {
    int r = idx >> 6, k = idx & 63;
    float a = 0.f, b = 0.f;
    for (int j = 0; j < 64; ++j) {
      float ww = wih[r*64 + j];
      a += ww * Wagg[j*128 + k];
      b += ww * Wagg[j*128 + 64 + k];
    }
    short ah = f2bf(a);
    WchH[idx] = ah; WchL[idx] = f2bf(a - bf2f(ah));
    short bh = f2bf(b);
    WceH[idx] = bh; WceL[idx] = f2bf(b - bf2f(bh));
    float wv = whh[idx];
    short hh = f2bf(wv);
    whhH[idx] = hh; whhL[idx] = f2bf(wv - bf2f(hh));
    if (idx < 192) {
      float s = 0.f;
      for (int j = 0; j < 64; ++j) s += wih[idx*64 + j] * bagg[j];
      bihA[idx] = s;
    }
  }
}

// ---------------- high-MLP gather: G[n] = sum_{e:dst=n} h_old[src[e]] ----------------
// lane = (er, fs): er=lane>>3 edge slot, fs=lane&7 feature segment (8 bf16 = 16B).
// One wave instruction gathers 8 edge-rows; 4 nodes interleaved per wave.
__global__ __launch_bounds__(256) void gather_G(
    const unsigned short* __restrict__ hb, const int* __restrict__ off,
    const int2* __restrict__ ep, float* __restrict__ G, int nNodes) {
  int tid = threadIdx.x, lane = tid & 63, w = tid >> 6;
  int er = lane >> 3, fs = lane & 7;
  int n0 = (blockIdx.x * 4 + w) * 4;
  if (n0 >= nNodes) return;
  int a[4], b[4];
#pragma unroll
  for (int j = 0; j < 4; ++j) {
    int n = n0 + j;
    a[j] = (n < nNodes) ? off[n] : 0;
    b[j] = (n < nNodes) ? off[n + 1] : 0;
  }
  float acc[4][8];
#pragma unroll
  for (int j = 0; j < 4; ++j)
#pragma unroll
    for (int q = 0; q < 8; ++q) acc[j][q] = 0.f;
  int mx = 0;
#pragma unroll
  for (int j = 0; j < 4; ++j) { int c = b[j] - a[j]; if (c > mx) mx = c; }
  for (int t = 0; t < mx; t += 8) {
#pragma unroll
    for (int j = 0; j < 4; ++j) {
      int idx = a[j] + t;
      int rem = b[j] - idx;            // wave-uniform
      if (rem > 0) {
        int e = idx + (er < rem ? er : rem - 1);
        int s = ep[e].y;
        ushort8 v = *(const ushort8*)(hb + (size_t)s * 64 + fs * 8);
        if (er < rem) {
#pragma unroll
          for (int q = 0; q < 8; ++q) acc[j][q] += us2f(v[q]);
        }
      }
    }
  }
  // butterfly-reduce across er (lane bits 3..5)
#pragma unroll
  for (int j = 0; j < 4; ++j)
#pragma unroll
    for (int q = 0; q < 8; ++q) {
      float v = acc[j][q];
      v += __shfl_xor(v, 8);
      v += __shfl_xor(v, 16);
      v += __shfl_xor(v, 32);
      acc[j][q] = v;
    }
  if (er == 0) {
#pragma unroll
    for (int j = 0; j < 4; ++j) {
      int n = n0 + j;
      if (n < nNodes) {
        f32x4 lo = {acc[j][0], acc[j][1], acc[j][2], acc[j][3]};
        f32x4 hi = {acc[j][4], acc[j][5], acc[j][6], acc[j][7]};
        *(f32x4*)(G + (size_t)n * 64 + fs * 8) = lo;
        *(f32x4*)(G + (size_t)n * 64 + fs * 8 + 4) = hi;
      }
    }
  }
}

// ---------------- dense layer: MFMA (gi & gh) + GRU, fully streaming ----------------
__global__ __launch_bounds__(256) void layer_dense(
    const float* __restrict__ h_old, const float* __restrict__ Esum,
    const float* __restrict__ G, const int* __restrict__ deg,
    const short* __restrict__ WceH, const short* __restrict__ WceL,
    const short* __restrict__ WchH, const short* __restrict__ WchL,
    const short* __restrict__ whhH, const short* __restrict__ whhL,
    const float* __restrict__ bihA, const float* __restrict__ bih,
    const float* __restrict__ bhh, float* __restrict__ h_new,
    unsigned short* __restrict__ h_newb, int nNodes) {
  int tid = threadIdx.x, lane = tid & 63, w = tid >> 6;
  int lr = lane & 15, lg = lane >> 4;
  int nb = blockIdx.x * 64;

  int arow = nb + w*16 + lr; if (arow >= nNodes) arow = nNodes - 1;
  short8 EsH[2], EsL[2], GHf[2], GLf[2], HH[2], HL[2];
#pragma unroll
  for (int kk = 0; kk < 2; ++kk) {
    split8(Esum + (size_t)arow*64 + kk*32 + lg*8, EsH[kk], EsL[kk]);
    split8(G + (size_t)arow*64 + kk*32 + lg*8, GHf[kk], GLf[kk]);
    split8(h_old + (size_t)arow*64 + kk*32 + lg*8, HH[kk], HL[kk]);
  }

  int row0 = nb + w*16 + lg*4;
  float degv[4];
#pragma unroll
  for (int i = 0; i < 4; ++i) {
    int n = row0 + i;
    degv[i] = (n < nNodes) ? (float)deg[n] : 0.f;
  }

  f32x4 gi[12], gh[12];
#pragma unroll
  for (int ct = 0; ct < 12; ++ct) {
    float bi = bih[ct*16 + lr], ba = bihA[ct*16 + lr], bh = bhh[ct*16 + lr];
#pragma unroll
    for (int i = 0; i < 4; ++i) { gi[ct][i] = bi + degv[i]*ba; gh[ct][i] = bh; }
  }

#pragma unroll
  for (int ct = 0; ct < 12; ++ct) {
    int wb = (ct*16 + lr)*64 + lg*8;
#pragma unroll
    for (int kk = 0; kk < 2; ++kk) {
      int o = wb + kk*32;
      short8 wceh = *(const short8*)(WceH + o);
      short8 wcel = *(const short8*)(WceL + o);
      short8 wchh = *(const short8*)(WchH + o);
      short8 wchl = *(const short8*)(WchL + o);
      short8 whh_h = *(const short8*)(whhH + o);
      short8 whh_l = *(const short8*)(whhL + o);
      gi[ct] = __builtin_amdgcn_mfma_f32_16x16x32_bf16(EsH[kk], wceh, gi[ct], 0,0,0);
      gi[ct] = __builtin_amdgcn_mfma_f32_16x16x32_bf16(EsL[kk], wceh, gi[ct], 0,0,0);
      gi[ct] = __builtin_amdgcn_mfma_f32_16x16x32_bf16(EsH[kk], wcel, gi[ct], 0,0,0);
      gi[ct] = __builtin_amdgcn_mfma_f32_16x16x32_bf16(GHf[kk], wchh, gi[ct], 0,0,0);
      gi[ct] = __builtin_amdgcn_mfma_f32_16x16x32_bf16(GLf[kk], wchh, gi[ct], 0,0,0);
      gi[ct] = __builtin_amdgcn_mfma_f32_16x16x32_bf16(GHf[kk], wchl, gi[ct], 0,0,0);
      gh[ct] = __builtin_amdgcn_mfma_f32_16x16x32_bf16(HH[kk], whh_h, gh[ct], 0,0,0);
      gh[ct] = __builtin_amdgcn_mfma_f32_16x16x32_bf16(HL[kk], whh_h, gh[ct], 0,0,0);
      gh[ct] = __builtin_amdgcn_mfma_f32_16x16x32_bf16(HH[kk], whh_l, gh[ct], 0,0,0);
    }
  }

  // GRU elementwise: lane holds cols ct*16+lr for rows row0..row0+3
#pragma unroll
  for (int ct = 0; ct < 4; ++ct)
#pragma unroll
    for (int i = 0; i < 4; ++i) {
      int n = row0 + i;
      if (n < nNodes) {
        int jh = ct*16 + lr;
        float r = 1.f/(1.f + expf(-(gi[ct][i] + gh[ct][i])));
        float z = 1.f/(1.f + expf(-(gi[ct+4][i] + gh[ct+4][i])));
        float nn = tanhf(gi[ct+8][i] + r * gh[ct+8][i]);
        float hv = h_old[(size_t)n*64 + jh];
        float hn = (1.f - z)*nn + z*hv;
        h_new[(size_t)n*64 + jh] = hn;
        h_newb[(size_t)n*64 + jh] = (unsigned short)f2bf(hn);
      }
    }
}

__global__ __launch_bounds__(256) void out_mlp(
    const float* __restrict__ h, const int* __restrict__ pm,
    const float* __restrict__ W1, const float* __restrict__ b1,
    const float* __restrict__ W2, const float* __restrict__ b2,
    float* __restrict__ out, int nPosts) {
  int tid = threadIdx.x;
  int lane = tid & 63;
  int p = blockIdx.x*4 + (tid >> 6);
  if (p >= nPosts) return;
  int n = pm[p];
  float v = h[(size_t)n*64 + lane];
  int row = lane & 31;
  float o = b1[row];
#pragma unroll
  for (int k = 0; k < 64; ++k) {
    float vb = __shfl(v, k);
    o += vb * W1[row*64 + k];
  }
  o = fmaxf(o, 0.f);
  float val = o * W2[row] * 0.5f;  // each row computed twice -> halve
#pragma unroll
  for (int offm = 32; offm > 0; offm >>= 1) val += __shfl_xor(val, offm);
  if (lane == 0) out[p] = 1.f/(1.f + expf(-(val + b2[0])));
}

static inline char* aln(char*& w, size_t bytes) {
  uintptr_t p = ((uintptr_t)w + 255) & ~(uintptr_t)255;
  char* r = (char*)p;
  w = r + bytes;
  return r;
}

extern "C" void kernel_launch(void* const* d_in, const int* in_sizes, int n_in,
                              void* d_out, int out_size, void* d_ws, size_t ws_size,
                              hipStream_t stream) {
  const float* X    = (const float*)d_in[0];
  const float* EA   = (const float*)d_in[1];
  const int*   EI   = (const int*)d_in[2];
  const int*   PM   = (const int*)d_in[3];
  const float* Wn   = (const float*)d_in[5];
  const float* bn   = (const float*)d_in[6];
  const float* We   = (const float*)d_in[7];
  const float* be   = (const float*)d_in[8];
  const float* Wagg = (const float*)d_in[9];
  const float* bagg = (const float*)d_in[10];
  const float* wih  = (const float*)d_in[11];
  const float* whh  = (const float*)d_in[12];
  const float* bih  = (const float*)d_in[13];
  const float* bhh  = (const float*)d_in[14];
  const float* W1   = (const float*)d_in[15];
  const float* b1   = (const float*)d_in[16];
  const float* W2   = (const float*)d_in[17];
  const float* b2   = (const float*)d_in[18];
  float* out = (float*)d_out;

  int nNodes = in_sizes[0] / 128;
  int nEdges = in_sizes[1] / 64;
  int nPosts = in_sizes[3];
  const int* src = EI;
  const int* dst = EI + nEdges;
  int nTiles = (nEdges + ETILE - 1) / ETILE;
  int nSB = (nNodes + 4095) / 4096;

  char* w = (char*)d_ws;
  float* h0   = (float*)aln(w, (size_t)nNodes * 64 * 4);
  float* h1   = (float*)aln(w, (size_t)nNodes * 64 * 4);
  unsigned short* h0b = (unsigned short*)aln(w, (size_t)nNodes * 64 * 2);
  unsigned short* h1b = (unsigned short*)aln(w, (size_t)nNodes * 64 * 2);
  float* Esum = (float*)aln(w, (size_t)nNodes * 64 * 4);
  float* G    = (float*)aln(w, (size_t)nNodes * 64 * 4);
  short* WceH = (short*)aln(w, 12288 * 2);
  short* WceL = (short*)aln(w, 12288 * 2);
  short* WchH = (short*)aln(w, 12288 * 2);
  short* WchL = (short*)aln(w, 12288 * 2);
  short* whhH = (short*)aln(w, 12288 * 2);
  short* whhL = (short*)aln(w, 12288 * 2);
  float* bihA = (float*)aln(w, 192 * 4);
  int*   off  = (int*)aln(w, (size_t)(nNodes + 1) * 4);
  int*   deg  = (int*)aln(w, (size_t)nNodes * 4);
  int*   cur  = (int*)aln(w, (size_t)nNodes * 4);
  int2*  ep   = (int2*)aln(w, (size_t)nEdges * 8);
  int*   tnlo = (int*)aln(w, (size_t)(nTiles + 1) * 4);
  int*   bsum = (int*)aln(w, (size_t)nSB * 4);
  int*   boff = (int*)aln(w, (size_t)nSB * 4);

  hipMemsetAsync(deg, 0, (size_t)nNodes * 4, stream);
  hipMemsetAsync(cur, 0, (size_t)nNodes * 4, stream);
  hipMemsetAsync(Esum, 0, (size_t)nNodes * 64 * 4, stream);

  hist_deg<<<2048, 256, 0, stream>>>(dst, deg, nEdges);
  scan_pass1<<<nSB, 256, 0, stream>>>(deg, bsum, nNodes);
  scan_pass2<<<1, 1, 0, stream>>>(bsum, boff, off, nSB, nNodes);
  scan_pass3<<<nSB, 256, 0, stream>>>(deg, boff, off, nNodes);
  fill_csr<<<2048, 256, 0, stream>>>(src, dst, off, cur, ep, nEdges);
  tile_nlo_k<<<(nTiles + 256) / 256, 256, 0, stream>>>(off, tnlo, nNodes, nTiles);

  node_encode<<<(nNodes + 63) / 64, 256, 0, stream>>>(X, Wn, bn, h0, h0b, nNodes);
  edge_encode_fused<<<nTiles, 256, 0, stream>>>(EA, We, be, off, ep, tnlo, Esum,
                                                nNodes, nEdges);
  make_combos<<<48, 256, 0, stream>>>(wih, Wagg, bagg, whh,
                                      WceH, WceL, WchH, WchL, whhH, whhL, bihA);

  // layer 1
  gather_G<<<(nNodes + 15) / 16, 256, 0, stream>>>(h0b, off, ep, G, nNodes);
  layer_dense<<<(nNodes + 63) / 64, 256, 0, stream>>>(
      h0, Esum, G, deg, WceH, WceL, WchH, WchL, whhH, whhL,
      bihA, bih, bhh, h1, h1b, nNodes);
  // layer 2
  gather_G<<<(nNodes + 15) / 16, 256, 0, stream>>>(h1b, off, ep, G, nNodes);
  layer_dense<<<(nNodes + 63) / 64, 256, 0, stream>>>(
      h1, Esum, G, deg, WceH, WceL, WchH, WchL, whhH, whhL,
      bihA, bih, bhh, h0, h0b, nNodes);

  out_mlp<<<(nPosts + 3) / 4, 256, 0, stream>>>(h0, PM, W1, b1, W2, b2, out, nPosts);
}